// Round 5
// baseline (7488.354 us; speedup 1.0000x reference)
//
#include <hip/hip_runtime.h>

#define NN 100000
#define NE 3200000
#define HM 30
#define HG 10
#define MAXK 26
#define OVF_CAP 8192

// ---- fused padded layer for TWO edges: out[32] = relu(in[NIN] @ W + b) ----
// One ds_read_b128 weight quad feeds 8 FMAs (2 edges x 4 outputs).
template<int NIN>
__device__ __forceinline__ void layer2_relu(const float4* __restrict__ W,
                                            const float4* __restrict__ b,
                                            const float* __restrict__ inA,
                                            const float* __restrict__ inB,
                                            float* __restrict__ outA,
                                            float* __restrict__ outB) {
    #pragma unroll
    for (int q = 0; q < 8; q++) {
        float4 aA = b[q];
        float4 aB = aA;
        #pragma unroll
        for (int i = 0; i < NIN; i++) {
            float4 w = W[i * 8 + q];
            float vA = inA[i], vB = inB[i];
            aA.x = fmaf(vA, w.x, aA.x); aB.x = fmaf(vB, w.x, aB.x);
            aA.y = fmaf(vA, w.y, aA.y); aB.y = fmaf(vB, w.y, aB.y);
            aA.z = fmaf(vA, w.z, aA.z); aB.z = fmaf(vB, w.z, aB.z);
            aA.w = fmaf(vA, w.w, aA.w); aB.w = fmaf(vB, w.w, aB.w);
        }
        outA[q * 4 + 0] = fmaxf(aA.x, 0.f); outB[q * 4 + 0] = fmaxf(aB.x, 0.f);
        outA[q * 4 + 1] = fmaxf(aA.y, 0.f); outB[q * 4 + 1] = fmaxf(aB.y, 0.f);
        outA[q * 4 + 2] = fmaxf(aA.z, 0.f); outB[q * 4 + 2] = fmaxf(aB.z, 0.f);
        outA[q * 4 + 3] = fmaxf(aA.w, 0.f); outB[q * 4 + 3] = fmaxf(aB.w, 0.f);
    }
}

// ---------------- Stage 0: pack node features + xw ----------------
__global__ __launch_bounds__(256) void pack_kernel(
    const float* __restrict__ x, const float* __restrict__ token,
    const float* __restrict__ Wc,
    float* __restrict__ xall8, float* __restrict__ xwp)
{
    __shared__ float sWc[6 * HG];
    if (threadIdx.x < 6 * HG) sWc[threadIdx.x] = Wc[threadIdx.x];
    __syncthreads();

    int n = blockIdx.x * 256 + threadIdx.x;
    if (n >= NN) return;

    float xa[6];
    xa[0] = x[n];
    #pragma unroll
    for (int i = 0; i < 5; i++) xa[1 + i] = token[n * 5 + i];

    float4* x4 = (float4*)xall8;
    x4[n * 2 + 0] = make_float4(xa[0], xa[1], xa[2], xa[3]);
    x4[n * 2 + 1] = make_float4(xa[4], xa[5], 0.f, 0.f);

    float w[12];
    #pragma unroll
    for (int k = 0; k < HG; k++) {
        float a = 0.f;
        #pragma unroll
        for (int i = 0; i < 6; i++) a = fmaf(xa[i], sWc[i * HG + k], a);
        w[k] = a;
    }
    w[10] = 0.f; w[11] = 0.f;
    float4* wp = (float4*)(xwp + (size_t)n * 12);
    wp[0] = make_float4(w[0], w[1], w[2], w[3]);
    wp[1] = make_float4(w[4], w[5], w[6], w[7]);
    wp[2] = make_float4(w[8], w[9], w[10], w[11]);
}

// ---------------- Stage 1: per-thread 2-edge MLP -> slots/overflow ----------
// LDS-issue bound: each b128 weight read feeds 8 FMAs. Single atomic stream
// (cnt) — R4 proved an extra deg atomic stream costs ~58us (+50MB WRITE).
__global__ __launch_bounds__(256, 3) void edge_mlp2e_kernel(
    const float* __restrict__ xall8,
    const float* __restrict__ eg, const float* __restrict__ ee,
    const float* __restrict__ gum, const int* __restrict__ eidx,
    const float* __restrict__ W0, const float* __restrict__ b0,
    const float* __restrict__ W1, const float* __restrict__ b1,
    const float* __restrict__ W2, const float* __restrict__ b2,
    const float* __restrict__ W3, const float* __restrict__ b3,
    const float* __restrict__ Wl, const float* __restrict__ bl,
    float2* __restrict__ slots, int* __restrict__ cnt,
    int* __restrict__ ohead, int* __restrict__ onxt,
    float* __restrict__ ovf_w, int* __restrict__ ovf_s, int* __restrict__ novf)
{
    __shared__ float4 sW0p[13 * 8];
    __shared__ float4 sW1p[30 * 8];
    __shared__ float4 sW2p[30 * 8];
    __shared__ float2 sW3[HM];
    __shared__ float4 sb0p[8], sb1p[8], sb2p[8];
    __shared__ float sb3[2], sWl, sbl;

    {
        float* f0 = (float*)sW0p;
        for (int idx = threadIdx.x; idx < 13 * 32; idx += 256) {
            int i = idx >> 5, j = idx & 31;
            f0[idx] = (j < HM) ? W0[i * HM + j] : 0.f;
        }
        float* f1 = (float*)sW1p;
        float* f2 = (float*)sW2p;
        for (int idx = threadIdx.x; idx < 30 * 32; idx += 256) {
            int i = idx >> 5, j = idx & 31;
            f1[idx] = (j < HM) ? W1[i * HM + j] : 0.f;
            f2[idx] = (j < HM) ? W2[i * HM + j] : 0.f;
        }
        if (threadIdx.x < 32) {
            int j = threadIdx.x;
            ((float*)sb0p)[j] = (j < HM) ? b0[j] : 0.f;
            ((float*)sb1p)[j] = (j < HM) ? b1[j] : 0.f;
            ((float*)sb2p)[j] = (j < HM) ? b2[j] : 0.f;
        }
        if (threadIdx.x < HM)
            sW3[threadIdx.x] = make_float2(W3[threadIdx.x * 2], W3[threadIdx.x * 2 + 1]);
        if (threadIdx.x < 2) sb3[threadIdx.x] = b3[threadIdx.x];
        if (threadIdx.x == 0) { sWl = Wl[0]; sbl = bl[0]; }
    }
    __syncthreads();

    int gtid = blockIdx.x * 256 + threadIdx.x;   // handles edges 2*gtid, 2*gtid+1
    int e0 = gtid * 2;
    int e1 = e0 + 1;

    const int2 se = ((const int2*)eidx)[gtid];            // src of e0,e1
    const int2 te = ((const int2*)(eidx + NE))[gtid];     // tgt of e0,e1
    const float2 ge = ((const float2*)eg)[gtid];

    const float4* x4 = (const float4*)xall8;
    float efA[13], efB[13];
    {
        float4 qa = x4[se.x * 2], qb = x4[se.x * 2 + 1];
        float4 qc = x4[te.x * 2], qd = x4[te.x * 2 + 1];
        efA[0]=qa.x; efA[1]=qa.y; efA[2]=qa.z; efA[3]=qa.w; efA[4]=qb.x; efA[5]=qb.y;
        efA[6]=qc.x; efA[7]=qc.y; efA[8]=qc.z; efA[9]=qc.w; efA[10]=qd.x; efA[11]=qd.y;
        efA[12]=ge.x;
    }
    {
        float4 qa = x4[se.y * 2], qb = x4[se.y * 2 + 1];
        float4 qc = x4[te.y * 2], qd = x4[te.y * 2 + 1];
        efB[0]=qa.x; efB[1]=qa.y; efB[2]=qa.z; efB[3]=qa.w; efB[4]=qb.x; efB[5]=qb.y;
        efB[6]=qc.x; efB[7]=qc.y; efB[8]=qc.z; efB[9]=qc.w; efB[10]=qd.x; efB[11]=qd.y;
        efB[12]=ge.y;
    }

    float hA[32], hB[32], gA[32], gB[32];
    layer2_relu<13>(sW0p, sb0p, efA, efB, hA, hB);
    layer2_relu<HM>(sW1p, sb1p, hA, hB, gA, gB);
    layer2_relu<HM>(sW2p, sb2p, gA, gB, hA, hB);

    float l0A = sb3[0], l1A = sb3[1];
    float l0B = sb3[0], l1B = sb3[1];
    #pragma unroll
    for (int i = 0; i < HM; i++) {
        float2 w = sW3[i];
        l0A = fmaf(hA[i], w.x, l0A); l1A = fmaf(hA[i], w.y, l1A);
        l0B = fmaf(hB[i], w.x, l0B); l1B = fmaf(hB[i], w.y, l1B);
    }

    const float4 gm = ((const float4*)gum)[gtid];   // (g0.x,g0.y,g1.x,g1.y)
    const float4 e2 = ((const float4*)ee)[gtid];    // (ee0.x,ee0.y,ee1.x,ee1.y)

    // forward: edge active iff argmax(logit+gumbel) == 0
    float ewA = 0.f, ewB = 0.f;
    if (!((l1A + gm.y) > (l0A + gm.x))) {
        float z = fmaf(e2.x, sWl, sbl);
        ewA = e2.y / (1.f + __expf(-z));
    }
    if (!((l1B + gm.w) > (l0B + gm.z))) {
        float z = fmaf(e2.z, sWl, sbl);
        ewB = e2.w / (1.f + __expf(-z));
    }

    if (ewA != 0.f) {
        int t = te.x;
        int slot = atomicAdd(&cnt[t], 1);
        if (slot < MAXK) {
            slots[(size_t)t * MAXK + slot] = make_float2(ewA, __int_as_float(se.x));
        } else {
            int i = atomicAdd(novf, 1);
            if (i < OVF_CAP) {
                ovf_w[i] = ewA; ovf_s[i] = se.x;
                onxt[i] = atomicExch(&ohead[t], i);
            }
        }
    }
    if (ewB != 0.f) {
        int t = te.y;
        int slot = atomicAdd(&cnt[t], 1);
        if (slot < MAXK) {
            slots[(size_t)t * MAXK + slot] = make_float2(ewB, __int_as_float(se.y));
        } else {
            int i = atomicAdd(novf, 1);
            if (i < OVF_CAP) {
                ovf_w[i] = ewB; ovf_s[i] = se.y;
                onxt[i] = atomicExch(&ohead[t], i);
            }
        }
    }
}

// ---------------- Stage 2: per-node deg from slots -> dis; scale xwp -------
__global__ __launch_bounds__(256) void node_deg_kernel(
    const float2* __restrict__ slots, const int* __restrict__ cnt,
    const int* __restrict__ ohead, const int* __restrict__ onxt,
    const float* __restrict__ ovf_w,
    float* __restrict__ xwp, float* __restrict__ dis)
{
    int n = blockIdx.x * 256 + threadIdx.x;
    if (n >= NN) return;

    int c = cnt[n];
    int cc = c < MAXK ? c : MAXK;
    float deg = 0.f;
    for (int j = 0; j < cc; j++) deg += slots[(size_t)n * MAXK + j].x;
    for (int i = ohead[n]; i >= 0; i = onxt[i]) deg += ovf_w[i];

    float d = rsqrtf(deg + 1.0f);   // +1 = self loop
    dis[n] = d;

    float4* wp = (float4*)(xwp + (size_t)n * 12);
    #pragma unroll
    for (int q = 0; q < 3; q++) {
        float4 v = wp[q];
        v.x *= d; v.y *= d; v.z *= d; v.w *= d;
        wp[q] = v;
    }
}

// ---------------- Stage 3: per-node gather + epilogue (no atomics) ----------
__global__ __launch_bounds__(256) void gather_out2_kernel(
    const float2* __restrict__ slots, const int* __restrict__ cnt,
    const int* __restrict__ ohead, const int* __restrict__ onxt,
    const float* __restrict__ ovf_w, const int* __restrict__ ovf_s,
    const float* __restrict__ z, const float* __restrict__ dis,
    const float* __restrict__ bc, const float* __restrict__ Wo,
    const float* __restrict__ bo, float* __restrict__ out)
{
    __shared__ float sbc[12], sWo[12], sbo;
    if (threadIdx.x < 12) {
        sbc[threadIdx.x] = (threadIdx.x < HG) ? bc[threadIdx.x] : 0.f;
        sWo[threadIdx.x] = (threadIdx.x < HG) ? Wo[threadIdx.x] : 0.f;
    }
    if (threadIdx.x == 0) sbo = bo[0];
    __syncthreads();

    int n = blockIdx.x * 256 + threadIdx.x;
    if (n >= NN) return;

    const float4* Z = (const float4*)z;
    float4 A0 = make_float4(0.f, 0.f, 0.f, 0.f), A1 = A0, A2 = A0;

    int c = cnt[n];
    int cc = c < MAXK ? c : MAXK;
    for (int j = 0; j < cc; j++) {
        float2 p = slots[(size_t)n * MAXK + j];
        float w = p.x;
        int s = __float_as_int(p.y);
        float4 z0 = Z[s * 3], z1 = Z[s * 3 + 1], z2 = Z[s * 3 + 2];
        A0.x = fmaf(w, z0.x, A0.x); A0.y = fmaf(w, z0.y, A0.y);
        A0.z = fmaf(w, z0.z, A0.z); A0.w = fmaf(w, z0.w, A0.w);
        A1.x = fmaf(w, z1.x, A1.x); A1.y = fmaf(w, z1.y, A1.y);
        A1.z = fmaf(w, z1.z, A1.z); A1.w = fmaf(w, z1.w, A1.w);
        A2.x = fmaf(w, z2.x, A2.x); A2.y = fmaf(w, z2.y, A2.y);
    }
    for (int i = ohead[n]; i >= 0; i = onxt[i]) {
        float w = ovf_w[i];
        int s = ovf_s[i];
        float4 z0 = Z[s * 3], z1 = Z[s * 3 + 1], z2 = Z[s * 3 + 2];
        A0.x = fmaf(w, z0.x, A0.x); A0.y = fmaf(w, z0.y, A0.y);
        A0.z = fmaf(w, z0.z, A0.z); A0.w = fmaf(w, z0.w, A0.w);
        A1.x = fmaf(w, z1.x, A1.x); A1.y = fmaf(w, z1.y, A1.y);
        A1.z = fmaf(w, z1.z, A1.z); A1.w = fmaf(w, z1.w, A1.w);
        A2.x = fmaf(w, z2.x, A2.x); A2.y = fmaf(w, z2.y, A2.y);
    }

    // self loop: + z[n] (w=1), then everything * dis[n], + bc
    float4 s0 = Z[n * 3], s1 = Z[n * 3 + 1], s2 = Z[n * 3 + 2];
    A0.x += s0.x; A0.y += s0.y; A0.z += s0.z; A0.w += s0.w;
    A1.x += s1.x; A1.y += s1.y; A1.z += s1.z; A1.w += s1.w;
    A2.x += s2.x; A2.y += s2.y;

    float d = dis[n];
    float v[10] = { A0.x, A0.y, A0.z, A0.w, A1.x, A1.y, A1.z, A1.w, A2.x, A2.y };
    float o = sbo;
    #pragma unroll
    for (int k = 0; k < HG; k++)
        o = fmaf(fmaf(v[k], d, sbc[k]), sWo[k], o);
    out[n] = 1.f / (1.f + __expf(-o));
}

// ================= Fallback path (Round-1 scatter) =================
__global__ __launch_bounds__(256) void edge_mlp_kernel(
    const float* __restrict__ x, const float* __restrict__ token,
    const float* __restrict__ eg, const float* __restrict__ ee,
    const float* __restrict__ gum, const int* __restrict__ eidx,
    const float* __restrict__ W0, const float* __restrict__ b0,
    const float* __restrict__ W1, const float* __restrict__ b1,
    const float* __restrict__ W2, const float* __restrict__ b2,
    const float* __restrict__ W3, const float* __restrict__ b3,
    const float* __restrict__ Wl, const float* __restrict__ bl,
    float* __restrict__ ew_out, float* __restrict__ deg)
{
    __shared__ float sW0[13 * HM];
    __shared__ float sW1[HM * HM];
    __shared__ float sW2[HM * HM];
    __shared__ float sW3f[HM * 2];
    __shared__ float sb0[HM], sb1[HM], sb2[HM], sb3[2];
    __shared__ float sWl, sbl;

    for (int i = threadIdx.x; i < 13 * HM; i += 256) sW0[i] = W0[i];
    for (int i = threadIdx.x; i < HM * HM; i += 256) sW1[i] = W1[i];
    for (int i = threadIdx.x; i < HM * HM; i += 256) sW2[i] = W2[i];
    for (int i = threadIdx.x; i < HM * 2; i += 256) sW3f[i] = W3[i];
    if (threadIdx.x < HM) {
        sb0[threadIdx.x] = b0[threadIdx.x];
        sb1[threadIdx.x] = b1[threadIdx.x];
        sb2[threadIdx.x] = b2[threadIdx.x];
    }
    if (threadIdx.x < 2) sb3[threadIdx.x] = b3[threadIdx.x];
    if (threadIdx.x == 0) { sWl = Wl[0]; sbl = bl[0]; }
    __syncthreads();

    int e = blockIdx.x * 256 + threadIdx.x;
    if (e >= NE) return;
    int s = eidx[e];
    int t = eidx[NE + e];

    float ef[13];
    ef[0] = x[s];
    #pragma unroll
    for (int i = 0; i < 5; i++) ef[1 + i] = token[s * 5 + i];
    ef[6] = x[t];
    #pragma unroll
    for (int i = 0; i < 5; i++) ef[7 + i] = token[t * 5 + i];
    ef[12] = eg[e];

    float h[HM], h2[HM];
    #pragma unroll
    for (int j = 0; j < HM; j++) {
        float a = sb0[j];
        #pragma unroll
        for (int i = 0; i < 13; i++) a = fmaf(ef[i], sW0[i * HM + j], a);
        h[j] = a > 0.f ? a : 0.f;
    }
    #pragma unroll
    for (int j = 0; j < HM; j++) {
        float a = sb1[j];
        #pragma unroll
        for (int i = 0; i < HM; i++) a = fmaf(h[i], sW1[i * HM + j], a);
        h2[j] = a > 0.f ? a : 0.f;
    }
    #pragma unroll
    for (int j = 0; j < HM; j++) {
        float a = sb2[j];
        #pragma unroll
        for (int i = 0; i < HM; i++) a = fmaf(h2[i], sW2[i * HM + j], a);
        h[j] = a > 0.f ? a : 0.f;
    }
    float l0 = sb3[0], l1 = sb3[1];
    #pragma unroll
    for (int i = 0; i < HM; i++) {
        l0 = fmaf(h[i], sW3f[i * 2 + 0], l0);
        l1 = fmaf(h[i], sW3f[i * 2 + 1], l1);
    }
    const float2 g2 = ((const float2*)gum)[e];
    float v0 = l0 + g2.x, v1 = l1 + g2.y;
    float ew = 0.f;
    if (!(v1 > v0)) {
        const float2 ee2 = ((const float2*)ee)[e];
        float z = fmaf(ee2.x, sWl, sbl);
        ew = ee2.y / (1.f + __expf(-z));
    }
    ew_out[e] = ew;
    if (ew != 0.f) atomicAdd(&deg[t], ew);
}

__global__ __launch_bounds__(256) void node_pre_kernel(
    const float* __restrict__ x, const float* __restrict__ token,
    const float* __restrict__ Wc, const float* __restrict__ deg,
    float* __restrict__ xw, float* __restrict__ dis)
{
    __shared__ float sWc[6 * HG];
    if (threadIdx.x < 6 * HG) sWc[threadIdx.x] = Wc[threadIdx.x];
    __syncthreads();
    int n = blockIdx.x * 256 + threadIdx.x;
    if (n >= NN) return;
    float xa[6];
    xa[0] = x[n];
    #pragma unroll
    for (int i = 0; i < 5; i++) xa[1 + i] = token[n * 5 + i];
    #pragma unroll
    for (int k = 0; k < HG; k++) {
        float a = 0.f;
        #pragma unroll
        for (int i = 0; i < 6; i++) a = fmaf(xa[i], sWc[i * HG + k], a);
        xw[n * HG + k] = a;
    }
    dis[n] = rsqrtf(deg[n] + 1.0f);
}

__global__ __launch_bounds__(256) void edge_scatter_kernel(
    const int* __restrict__ eidx, const float* __restrict__ ew,
    const float* __restrict__ dis, const float* __restrict__ xw,
    float* __restrict__ agg)
{
    int e = blockIdx.x * 256 + threadIdx.x;
    if (e >= NE) return;
    float w = ew[e];
    if (w == 0.f) return;
    int s = eidx[e];
    int t = eidx[NE + e];
    float norm = dis[s] * w * dis[t];
    #pragma unroll
    for (int k = 0; k < HG; k++)
        atomicAdd(&agg[t * HG + k], norm * xw[s * HG + k]);
}

__global__ __launch_bounds__(256) void node_out_kernel(
    const float* __restrict__ agg, const float* __restrict__ xw,
    const float* __restrict__ dis, const float* __restrict__ bc,
    const float* __restrict__ Wo, const float* __restrict__ bo,
    float* __restrict__ out)
{
    __shared__ float sbc[HG], sWo[HG], sbo;
    if (threadIdx.x < HG) { sbc[threadIdx.x] = bc[threadIdx.x]; sWo[threadIdx.x] = Wo[threadIdx.x]; }
    if (threadIdx.x == 0) sbo = bo[0];
    __syncthreads();
    int n = blockIdx.x * 256 + threadIdx.x;
    if (n >= NN) return;
    float d = dis[n];
    float self = d * d;
    float acc = sbo;
    #pragma unroll
    for (int k = 0; k < HG; k++) {
        float v = agg[n * HG + k] + xw[n * HG + k] * self + sbc[k];
        acc = fmaf(v, sWo[k], acc);
    }
    out[n] = 1.f / (1.f + __expf(-acc));
}

extern "C" void kernel_launch(void* const* d_in, const int* in_sizes, int n_in,
                              void* d_out, int out_size, void* d_ws, size_t ws_size,
                              hipStream_t stream) {
    const float* x   = (const float*)d_in[0];
    const float* tok = (const float*)d_in[1];
    const float* eg  = (const float*)d_in[2];
    const float* ee  = (const float*)d_in[3];
    const float* gum = (const float*)d_in[4];
    const int*   ei  = (const int*)d_in[5];
    const float* W0  = (const float*)d_in[6];
    const float* b0  = (const float*)d_in[7];
    const float* W1  = (const float*)d_in[8];
    const float* b1  = (const float*)d_in[9];
    const float* W2  = (const float*)d_in[10];
    const float* b2  = (const float*)d_in[11];
    const float* W3  = (const float*)d_in[12];
    const float* b3  = (const float*)d_in[13];
    const float* Wl  = (const float*)d_in[14];
    const float* bl  = (const float*)d_in[15];
    const float* Wc  = (const float*)d_in[16];
    const float* bc  = (const float*)d_in[17];
    const float* Wo  = (const float*)d_in[18];
    const float* bo  = (const float*)d_in[19];
    float* out = (float*)d_out;

    dim3 blk(256);
    dim3 e2grid(NE / 512);              // 2 edges/thread: 6250 blocks
    dim3 egrid(NE / 256);               // fallback: 12500
    dim3 ngrid((NN + 255) / 256);

    // New-path ws layout (float offsets) — same as Round 3 (proven to fit)
    size_t off_xall8 = 0;                                 // NN*8
    size_t off_z     = off_xall8 + (size_t)NN * 8;        // NN*12
    size_t off_slots = off_z + (size_t)NN * 12;           // NN*MAXK*2
    size_t off_cnt   = off_slots + (size_t)NN * MAXK * 2; // NN int
    size_t off_novf  = off_cnt + NN;                      // 1 int
    size_t off_dis   = off_novf + 1;                      // NN
    size_t off_ohead = off_dis + NN;                      // NN int
    size_t off_ovfw  = off_ohead + NN;                    // OVF_CAP
    size_t off_ovfs  = off_ovfw + OVF_CAP;                // OVF_CAP int
    size_t off_onxt  = off_ovfs + OVF_CAP;                // OVF_CAP int
    size_t need_new  = (off_onxt + OVF_CAP) * sizeof(float);

    if (ws_size >= need_new) {
        float*  ws    = (float*)d_ws;
        float*  xall8 = ws + off_xall8;
        float*  z     = ws + off_z;
        float2* slots = (float2*)(ws + off_slots);
        int*    cnt   = (int*)(ws + off_cnt);
        int*    novf  = (int*)(ws + off_novf);
        float*  dis   = ws + off_dis;
        int*    ohead = (int*)(ws + off_ohead);
        float*  ovf_w = ws + off_ovfw;
        int*    ovf_s = (int*)(ws + off_ovfs);
        int*    onxt  = (int*)(ws + off_onxt);

        hipMemsetAsync(cnt, 0, (size_t)(NN + 1) * sizeof(int), stream);   // cnt + novf
        hipMemsetAsync(ohead, 0xFF, (size_t)NN * sizeof(int), stream);    // ohead = -1

        pack_kernel<<<ngrid, blk, 0, stream>>>(x, tok, Wc, xall8, z);
        edge_mlp2e_kernel<<<e2grid, blk, 0, stream>>>(xall8, eg, ee, gum, ei,
                                                      W0, b0, W1, b1, W2, b2, W3, b3,
                                                      Wl, bl, slots, cnt,
                                                      ohead, onxt, ovf_w, ovf_s, novf);
        node_deg_kernel<<<ngrid, blk, 0, stream>>>(slots, cnt, ohead, onxt, ovf_w,
                                                   z, dis);
        gather_out2_kernel<<<ngrid, blk, 0, stream>>>(slots, cnt, ohead, onxt,
                                                      ovf_w, ovf_s, z, dis,
                                                      bc, Wo, bo, out);
    } else {
        // Fallback: Round-1 scatter layout: [ew: NE][deg: NN][agg: NN*HG][xw: NN*HG][dis: NN]
        float* ws  = (float*)d_ws;
        float* ew  = ws;
        float* deg = ew + NE;
        float* agg = deg + NN;
        float* xw  = agg + (size_t)NN * HG;
        float* dis = xw + (size_t)NN * HG;

        hipMemsetAsync(deg, 0, (size_t)(NN + (size_t)NN * HG) * sizeof(float), stream);
        edge_mlp_kernel<<<egrid, blk, 0, stream>>>(x, tok, eg, ee, gum, ei,
                                                   W0, b0, W1, b1, W2, b2, W3, b3,
                                                   Wl, bl, ew, deg);
        node_pre_kernel<<<ngrid, blk, 0, stream>>>(x, tok, Wc, deg, xw, dis);
        edge_scatter_kernel<<<egrid, blk, 0, stream>>>(ei, ew, dis, xw, agg);
        node_out_kernel<<<ngrid, blk, 0, stream>>>(agg, xw, dis, bc, Wo, bo, out);
    }
}

// Round 6
// 2205.418 us; speedup vs baseline: 3.3954x; 3.3954x over previous
//
#include <hip/hip_runtime.h>

#define NN 100000
#define NE 3200000
#define HM 30
#define HG 10
#define MAXK 26
#define OVF_CAP 8192

// ---------------- Stage 0: pack node features + xw ----------------
__global__ __launch_bounds__(256) void pack_kernel(
    const float* __restrict__ x, const float* __restrict__ token,
    const float* __restrict__ Wc,
    float* __restrict__ xall8, float* __restrict__ xwp)
{
    int n = blockIdx.x * 256 + threadIdx.x;
    if (n >= NN) return;

    float xa[6];
    xa[0] = x[n];
    #pragma unroll
    for (int i = 0; i < 5; i++) xa[1 + i] = token[n * 5 + i];

    float4* x4 = (float4*)xall8;
    x4[n * 2 + 0] = make_float4(xa[0], xa[1], xa[2], xa[3]);
    x4[n * 2 + 1] = make_float4(xa[4], xa[5], 0.f, 0.f);

    float w[12];
    #pragma unroll
    for (int k = 0; k < HG; k++) {
        float a = 0.f;
        #pragma unroll
        for (int i = 0; i < 6; i++) a = fmaf(xa[i], Wc[i * HG + k], a);  // uniform -> s_load
        w[k] = a;
    }
    w[10] = 0.f; w[11] = 0.f;
    float4* wp = (float4*)(xwp + (size_t)n * 12);
    wp[0] = make_float4(w[0], w[1], w[2], w[3]);
    wp[1] = make_float4(w[4], w[5], w[6], w[7]);
    wp[2] = make_float4(w[8], w[9], w[10], w[11]);
}

// ---------------- Stage 1: per-edge MLP, weights via SGPR (scalar pipe) -----
// Weights are wave-uniform: constant-index reads off kernel-arg pointers emit
// s_load -> SGPR, and FMAs use the SGPR operand directly. No LDS staging:
// the LDS->VGPR return path (256 B/cyc/CU) capped R2/R3 at ~50% VALU.
__global__ __launch_bounds__(256) void edge_mlp3_kernel(
    const float* __restrict__ xall8,
    const float* __restrict__ eg, const float* __restrict__ ee,
    const float* __restrict__ gum, const int* __restrict__ eidx,
    const float* __restrict__ W0, const float* __restrict__ b0,
    const float* __restrict__ W1, const float* __restrict__ b1,
    const float* __restrict__ W2, const float* __restrict__ b2,
    const float* __restrict__ W3, const float* __restrict__ b3,
    const float* __restrict__ Wl, const float* __restrict__ bl,
    float2* __restrict__ slots, int* __restrict__ cnt,
    int* __restrict__ ohead, int* __restrict__ onxt,
    float* __restrict__ ovf_w, int* __restrict__ ovf_s, int* __restrict__ novf)
{
    int e = blockIdx.x * 256 + threadIdx.x;   // NE == 12500*256 exactly
    int s = eidx[e];
    int t = eidx[NE + e];

    const float4* x4 = (const float4*)xall8;
    float4 qa = x4[s * 2], qb = x4[s * 2 + 1];
    float4 qc = x4[t * 2], qd = x4[t * 2 + 1];
    float ef[13] = { qa.x, qa.y, qa.z, qa.w, qb.x, qb.y,
                     qc.x, qc.y, qc.z, qc.w, qd.x, qd.y, eg[e] };

    float h[HM], h2[HM];
    #pragma unroll
    for (int j = 0; j < HM; j++) {
        float a = b0[j];
        #pragma unroll
        for (int i = 0; i < 13; i++) a = fmaf(ef[i], W0[i * HM + j], a);
        h[j] = fmaxf(a, 0.f);
    }
    #pragma unroll
    for (int j = 0; j < HM; j++) {
        float a = b1[j];
        #pragma unroll
        for (int i = 0; i < HM; i++) a = fmaf(h[i], W1[i * HM + j], a);
        h2[j] = fmaxf(a, 0.f);
    }
    #pragma unroll
    for (int j = 0; j < HM; j++) {
        float a = b2[j];
        #pragma unroll
        for (int i = 0; i < HM; i++) a = fmaf(h2[i], W2[i * HM + j], a);
        h[j] = fmaxf(a, 0.f);
    }
    float l0 = b3[0], l1 = b3[1];
    #pragma unroll
    for (int i = 0; i < HM; i++) {
        l0 = fmaf(h[i], W3[i * 2 + 0], l0);
        l1 = fmaf(h[i], W3[i * 2 + 1], l1);
    }

    const float2 g2 = ((const float2*)gum)[e];
    float v0 = l0 + g2.x;
    float v1 = l1 + g2.y;

    // forward: edge_value = (v1 > v0) ? 1 : 0; active iff edge_value == 0
    float ew = 0.f;
    if (!(v1 > v0)) {
        const float2 e2 = ((const float2*)ee)[e];
        float z = fmaf(e2.x, Wl[0], bl[0]);
        ew = e2.y / (1.f + __expf(-z));
    }
    if (ew != 0.f) {
        int slot = atomicAdd(&cnt[t], 1);
        if (slot < MAXK) {
            slots[(size_t)t * MAXK + slot] = make_float2(ew, __int_as_float(s));
        } else {
            int i = atomicAdd(novf, 1);
            if (i < OVF_CAP) {
                ovf_w[i] = ew;
                ovf_s[i] = s;
                onxt[i] = atomicExch(&ohead[t], i);
            }
        }
    }
}

// ---------------- Stage 2: per-node deg from slots -> dis; scale xwp -------
__global__ __launch_bounds__(256) void node_deg_kernel(
    const float2* __restrict__ slots, const int* __restrict__ cnt,
    const int* __restrict__ ohead, const int* __restrict__ onxt,
    const float* __restrict__ ovf_w,
    float* __restrict__ xwp, float* __restrict__ dis)
{
    int n = blockIdx.x * 256 + threadIdx.x;
    if (n >= NN) return;

    int c = cnt[n];
    int cc = c < MAXK ? c : MAXK;
    float deg = 0.f;
    for (int j = 0; j < cc; j++) deg += slots[(size_t)n * MAXK + j].x;
    for (int i = ohead[n]; i >= 0; i = onxt[i]) deg += ovf_w[i];

    float d = rsqrtf(deg + 1.0f);   // +1 = self loop
    dis[n] = d;

    float4* wp = (float4*)(xwp + (size_t)n * 12);
    #pragma unroll
    for (int q = 0; q < 3; q++) {
        float4 v = wp[q];
        v.x *= d; v.y *= d; v.z *= d; v.w *= d;
        wp[q] = v;
    }
}

// ---------------- Stage 3: per-node gather + epilogue (no atomics) ----------
__global__ __launch_bounds__(256) void gather_out2_kernel(
    const float2* __restrict__ slots, const int* __restrict__ cnt,
    const int* __restrict__ ohead, const int* __restrict__ onxt,
    const float* __restrict__ ovf_w, const int* __restrict__ ovf_s,
    const float* __restrict__ z, const float* __restrict__ dis,
    const float* __restrict__ bc, const float* __restrict__ Wo,
    const float* __restrict__ bo, float* __restrict__ out)
{
    int n = blockIdx.x * 256 + threadIdx.x;
    if (n >= NN) return;

    const float4* Z = (const float4*)z;
    float4 A0 = make_float4(0.f, 0.f, 0.f, 0.f), A1 = A0, A2 = A0;

    int c = cnt[n];
    int cc = c < MAXK ? c : MAXK;
    for (int j = 0; j < cc; j++) {
        float2 p = slots[(size_t)n * MAXK + j];
        float w = p.x;
        int s = __float_as_int(p.y);
        float4 z0 = Z[s * 3], z1 = Z[s * 3 + 1], z2 = Z[s * 3 + 2];
        A0.x = fmaf(w, z0.x, A0.x); A0.y = fmaf(w, z0.y, A0.y);
        A0.z = fmaf(w, z0.z, A0.z); A0.w = fmaf(w, z0.w, A0.w);
        A1.x = fmaf(w, z1.x, A1.x); A1.y = fmaf(w, z1.y, A1.y);
        A1.z = fmaf(w, z1.z, A1.z); A1.w = fmaf(w, z1.w, A1.w);
        A2.x = fmaf(w, z2.x, A2.x); A2.y = fmaf(w, z2.y, A2.y);
    }
    for (int i = ohead[n]; i >= 0; i = onxt[i]) {
        float w = ovf_w[i];
        int s = ovf_s[i];
        float4 z0 = Z[s * 3], z1 = Z[s * 3 + 1], z2 = Z[s * 3 + 2];
        A0.x = fmaf(w, z0.x, A0.x); A0.y = fmaf(w, z0.y, A0.y);
        A0.z = fmaf(w, z0.z, A0.z); A0.w = fmaf(w, z0.w, A0.w);
        A1.x = fmaf(w, z1.x, A1.x); A1.y = fmaf(w, z1.y, A1.y);
        A1.z = fmaf(w, z1.z, A1.z); A1.w = fmaf(w, z1.w, A1.w);
        A2.x = fmaf(w, z2.x, A2.x); A2.y = fmaf(w, z2.y, A2.y);
    }

    // self loop: + z[n] (w=1), then everything * dis[n], + bc
    float4 s0 = Z[n * 3], s1 = Z[n * 3 + 1], s2 = Z[n * 3 + 2];
    A0.x += s0.x; A0.y += s0.y; A0.z += s0.z; A0.w += s0.w;
    A1.x += s1.x; A1.y += s1.y; A1.z += s1.z; A1.w += s1.w;
    A2.x += s2.x; A2.y += s2.y;

    float d = dis[n];
    float v[10] = { A0.x, A0.y, A0.z, A0.w, A1.x, A1.y, A1.z, A1.w, A2.x, A2.y };
    float o = bo[0];
    #pragma unroll
    for (int k = 0; k < HG; k++)
        o = fmaf(fmaf(v[k], d, bc[k]), Wo[k], o);   // bc/Wo uniform -> s_load
    out[n] = 1.f / (1.f + __expf(-o));
}

// ================= Fallback path (Round-1 scatter) =================
__global__ __launch_bounds__(256) void edge_mlp_kernel(
    const float* __restrict__ x, const float* __restrict__ token,
    const float* __restrict__ eg, const float* __restrict__ ee,
    const float* __restrict__ gum, const int* __restrict__ eidx,
    const float* __restrict__ W0, const float* __restrict__ b0,
    const float* __restrict__ W1, const float* __restrict__ b1,
    const float* __restrict__ W2, const float* __restrict__ b2,
    const float* __restrict__ W3, const float* __restrict__ b3,
    const float* __restrict__ Wl, const float* __restrict__ bl,
    float* __restrict__ ew_out, float* __restrict__ deg)
{
    int e = blockIdx.x * 256 + threadIdx.x;
    if (e >= NE) return;
    int s = eidx[e];
    int t = eidx[NE + e];

    float ef[13];
    ef[0] = x[s];
    #pragma unroll
    for (int i = 0; i < 5; i++) ef[1 + i] = token[s * 5 + i];
    ef[6] = x[t];
    #pragma unroll
    for (int i = 0; i < 5; i++) ef[7 + i] = token[t * 5 + i];
    ef[12] = eg[e];

    float h[HM], h2[HM];
    #pragma unroll
    for (int j = 0; j < HM; j++) {
        float a = b0[j];
        #pragma unroll
        for (int i = 0; i < 13; i++) a = fmaf(ef[i], W0[i * HM + j], a);
        h[j] = fmaxf(a, 0.f);
    }
    #pragma unroll
    for (int j = 0; j < HM; j++) {
        float a = b1[j];
        #pragma unroll
        for (int i = 0; i < HM; i++) a = fmaf(h[i], W1[i * HM + j], a);
        h2[j] = fmaxf(a, 0.f);
    }
    #pragma unroll
    for (int j = 0; j < HM; j++) {
        float a = b2[j];
        #pragma unroll
        for (int i = 0; i < HM; i++) a = fmaf(h2[i], W2[i * HM + j], a);
        h[j] = fmaxf(a, 0.f);
    }
    float l0 = b3[0], l1 = b3[1];
    #pragma unroll
    for (int i = 0; i < HM; i++) {
        l0 = fmaf(h[i], W3[i * 2 + 0], l0);
        l1 = fmaf(h[i], W3[i * 2 + 1], l1);
    }
    const float2 g2 = ((const float2*)gum)[e];
    float v0 = l0 + g2.x, v1 = l1 + g2.y;
    float ew = 0.f;
    if (!(v1 > v0)) {
        const float2 ee2 = ((const float2*)ee)[e];
        float z = fmaf(ee2.x, Wl[0], bl[0]);
        ew = ee2.y / (1.f + __expf(-z));
    }
    ew_out[e] = ew;
    if (ew != 0.f) atomicAdd(&deg[t], ew);
}

__global__ __launch_bounds__(256) void node_pre_kernel(
    const float* __restrict__ x, const float* __restrict__ token,
    const float* __restrict__ Wc, const float* __restrict__ deg,
    float* __restrict__ xw, float* __restrict__ dis)
{
    int n = blockIdx.x * 256 + threadIdx.x;
    if (n >= NN) return;
    float xa[6];
    xa[0] = x[n];
    #pragma unroll
    for (int i = 0; i < 5; i++) xa[1 + i] = token[n * 5 + i];
    #pragma unroll
    for (int k = 0; k < HG; k++) {
        float a = 0.f;
        #pragma unroll
        for (int i = 0; i < 6; i++) a = fmaf(xa[i], Wc[i * HG + k], a);
        xw[n * HG + k] = a;
    }
    dis[n] = rsqrtf(deg[n] + 1.0f);
}

__global__ __launch_bounds__(256) void edge_scatter_kernel(
    const int* __restrict__ eidx, const float* __restrict__ ew,
    const float* __restrict__ dis, const float* __restrict__ xw,
    float* __restrict__ agg)
{
    int e = blockIdx.x * 256 + threadIdx.x;
    if (e >= NE) return;
    float w = ew[e];
    if (w == 0.f) return;
    int s = eidx[e];
    int t = eidx[NE + e];
    float norm = dis[s] * w * dis[t];
    #pragma unroll
    for (int k = 0; k < HG; k++)
        atomicAdd(&agg[t * HG + k], norm * xw[s * HG + k]);
}

__global__ __launch_bounds__(256) void node_out_kernel(
    const float* __restrict__ agg, const float* __restrict__ xw,
    const float* __restrict__ dis, const float* __restrict__ bc,
    const float* __restrict__ Wo, const float* __restrict__ bo,
    float* __restrict__ out)
{
    int n = blockIdx.x * 256 + threadIdx.x;
    if (n >= NN) return;
    float d = dis[n];
    float self = d * d;
    float acc = bo[0];
    #pragma unroll
    for (int k = 0; k < HG; k++) {
        float v = agg[n * HG + k] + xw[n * HG + k] * self + bc[k];
        acc = fmaf(v, Wo[k], acc);
    }
    out[n] = 1.f / (1.f + __expf(-acc));
}

extern "C" void kernel_launch(void* const* d_in, const int* in_sizes, int n_in,
                              void* d_out, int out_size, void* d_ws, size_t ws_size,
                              hipStream_t stream) {
    const float* x   = (const float*)d_in[0];
    const float* tok = (const float*)d_in[1];
    const float* eg  = (const float*)d_in[2];
    const float* ee  = (const float*)d_in[3];
    const float* gum = (const float*)d_in[4];
    const int*   ei  = (const int*)d_in[5];
    const float* W0  = (const float*)d_in[6];
    const float* b0  = (const float*)d_in[7];
    const float* W1  = (const float*)d_in[8];
    const float* b1  = (const float*)d_in[9];
    const float* W2  = (const float*)d_in[10];
    const float* b2  = (const float*)d_in[11];
    const float* W3  = (const float*)d_in[12];
    const float* b3  = (const float*)d_in[13];
    const float* Wl  = (const float*)d_in[14];
    const float* bl  = (const float*)d_in[15];
    const float* Wc  = (const float*)d_in[16];
    const float* bc  = (const float*)d_in[17];
    const float* Wo  = (const float*)d_in[18];
    const float* bo  = (const float*)d_in[19];
    float* out = (float*)d_out;

    dim3 blk(256);
    dim3 egrid(NE / 256);               // exact: 12500
    dim3 ngrid((NN + 255) / 256);

    // New-path ws layout (float offsets) — same as Round 3 (proven to fit)
    size_t off_xall8 = 0;                                 // NN*8
    size_t off_z     = off_xall8 + (size_t)NN * 8;        // NN*12
    size_t off_slots = off_z + (size_t)NN * 12;           // NN*MAXK*2
    size_t off_cnt   = off_slots + (size_t)NN * MAXK * 2; // NN int
    size_t off_novf  = off_cnt + NN;                      // 1 int
    size_t off_dis   = off_novf + 1;                      // NN
    size_t off_ohead = off_dis + NN;                      // NN int
    size_t off_ovfw  = off_ohead + NN;                    // OVF_CAP
    size_t off_ovfs  = off_ovfw + OVF_CAP;                // OVF_CAP int
    size_t off_onxt  = off_ovfs + OVF_CAP;                // OVF_CAP int
    size_t need_new  = (off_onxt + OVF_CAP) * sizeof(float);

    if (ws_size >= need_new) {
        float*  ws    = (float*)d_ws;
        float*  xall8 = ws + off_xall8;
        float*  z     = ws + off_z;
        float2* slots = (float2*)(ws + off_slots);
        int*    cnt   = (int*)(ws + off_cnt);
        int*    novf  = (int*)(ws + off_novf);
        float*  dis   = ws + off_dis;
        int*    ohead = (int*)(ws + off_ohead);
        float*  ovf_w = ws + off_ovfw;
        int*    ovf_s = (int*)(ws + off_ovfs);
        int*    onxt  = (int*)(ws + off_onxt);

        hipMemsetAsync(cnt, 0, (size_t)(NN + 1) * sizeof(int), stream);   // cnt + novf
        hipMemsetAsync(ohead, 0xFF, (size_t)NN * sizeof(int), stream);    // ohead = -1

        pack_kernel<<<ngrid, blk, 0, stream>>>(x, tok, Wc, xall8, z);
        edge_mlp3_kernel<<<egrid, blk, 0, stream>>>(xall8, eg, ee, gum, ei,
                                                    W0, b0, W1, b1, W2, b2, W3, b3,
                                                    Wl, bl, slots, cnt,
                                                    ohead, onxt, ovf_w, ovf_s, novf);
        node_deg_kernel<<<ngrid, blk, 0, stream>>>(slots, cnt, ohead, onxt, ovf_w,
                                                   z, dis);
        gather_out2_kernel<<<ngrid, blk, 0, stream>>>(slots, cnt, ohead, onxt,
                                                      ovf_w, ovf_s, z, dis,
                                                      bc, Wo, bo, out);
    } else {
        // Fallback: Round-1 scatter layout: [ew: NE][deg: NN][agg: NN*HG][xw: NN*HG][dis: NN]
        float* ws  = (float*)d_ws;
        float* ew  = ws;
        float* deg = ew + NE;
        float* agg = deg + NN;
        float* xw  = agg + (size_t)NN * HG;
        float* dis = xw + (size_t)NN * HG;

        hipMemsetAsync(deg, 0, (size_t)(NN + (size_t)NN * HG) * sizeof(float), stream);
        edge_mlp_kernel<<<egrid, blk, 0, stream>>>(x, tok, eg, ee, gum, ei,
                                                   W0, b0, W1, b1, W2, b2, W3, b3,
                                                   Wl, bl, ew, deg);
        node_pre_kernel<<<ngrid, blk, 0, stream>>>(x, tok, Wc, deg, xw, dis);
        edge_scatter_kernel<<<egrid, blk, 0, stream>>>(ei, ew, dis, xw, agg);
        node_out_kernel<<<ngrid, blk, 0, stream>>>(agg, xw, dis, bc, Wo, bo, out);
    }
}

// Round 7
// 455.648 us; speedup vs baseline: 16.4345x; 4.8402x over previous
//
#include <hip/hip_runtime.h>

#define NN 100000
#define NE 3200000
#define HM 30
#define HG 10
#define MAXK 26
#define OVF_CAP 8192

// ---------------- Stage 0: pack node features + xw ----------------
__global__ __launch_bounds__(256) void pack_kernel(
    const float* __restrict__ x, const float* __restrict__ token,
    const float* __restrict__ Wc,
    float* __restrict__ xall8, float* __restrict__ xwp)
{
    int n = blockIdx.x * 256 + threadIdx.x;
    if (n >= NN) return;

    float xa[6];
    xa[0] = x[n];
    #pragma unroll
    for (int i = 0; i < 5; i++) xa[1 + i] = token[n * 5 + i];

    float4* x4 = (float4*)xall8;
    x4[n * 2 + 0] = make_float4(xa[0], xa[1], xa[2], xa[3]);
    x4[n * 2 + 1] = make_float4(xa[4], xa[5], 0.f, 0.f);

    float w[12];
    #pragma unroll
    for (int k = 0; k < HG; k++) {
        float a = 0.f;
        #pragma unroll
        for (int i = 0; i < 6; i++) a = fmaf(xa[i], Wc[i * HG + k], a);
        w[k] = a;
    }
    w[10] = 0.f; w[11] = 0.f;
    float4* wp = (float4*)(xwp + (size_t)n * 12);
    wp[0] = make_float4(w[0], w[1], w[2], w[3]);
    wp[1] = make_float4(w[4], w[5], w[6], w[7]);
    wp[2] = make_float4(w[8], w[9], w[10], w[11]);
}

// ---------------- Stage 1: per-edge MLP, LDS weights as column-PAIRS --------
// ds_read_b64 per (row, output-pair): half the LDS instructions of R2's b32
// path at the same per-byte LDS cost; only 2 scalar accumulators live (R2-
// sized live set, ~55 VGPR — avoids R3's float4-acc VALU bloat and R5's
// scratch spill). Each b64 feeds 2 FMAs.
__global__ __launch_bounds__(256) void edge_mlp4_kernel(
    const float* __restrict__ xall8,
    const float* __restrict__ eg, const float* __restrict__ ee,
    const float* __restrict__ gum, const int* __restrict__ eidx,
    const float* __restrict__ W0, const float* __restrict__ b0,
    const float* __restrict__ W1, const float* __restrict__ b1,
    const float* __restrict__ W2, const float* __restrict__ b2,
    const float* __restrict__ W3, const float* __restrict__ b3,
    const float* __restrict__ Wl, const float* __restrict__ bl,
    float* __restrict__ slots_w, int* __restrict__ slots_s,
    int* __restrict__ cnt,
    int* __restrict__ ohead, int* __restrict__ onxt,
    float* __restrict__ ovf_w, int* __restrict__ ovf_s, int* __restrict__ novf)
{
    __shared__ float2 sW0p[15 * 13];   // [jp][i] = (W0[i][2jp], W0[i][2jp+1])
    __shared__ float2 sW1p[15 * 30];
    __shared__ float2 sW2p[15 * 30];
    __shared__ float2 sW3[HM];         // row i of 30x2 = float2
    __shared__ float2 sb0p[15], sb1p[15], sb2p[15];
    __shared__ float sb3[2], sWl, sbl;

    for (int idx = threadIdx.x; idx < 15 * 13; idx += 256) {
        int jp = idx / 13, i = idx - jp * 13;
        sW0p[idx] = make_float2(W0[i * HM + 2 * jp], W0[i * HM + 2 * jp + 1]);
    }
    for (int idx = threadIdx.x; idx < 15 * 30; idx += 256) {
        int jp = idx / 30, i = idx - jp * 30;
        sW1p[idx] = make_float2(W1[i * HM + 2 * jp], W1[i * HM + 2 * jp + 1]);
        sW2p[idx] = make_float2(W2[i * HM + 2 * jp], W2[i * HM + 2 * jp + 1]);
    }
    if (threadIdx.x < HM) sW3[threadIdx.x] = ((const float2*)W3)[threadIdx.x];
    if (threadIdx.x < 15) {
        int j = threadIdx.x;
        sb0p[j] = make_float2(b0[2 * j], b0[2 * j + 1]);
        sb1p[j] = make_float2(b1[2 * j], b1[2 * j + 1]);
        sb2p[j] = make_float2(b2[2 * j], b2[2 * j + 1]);
    }
    if (threadIdx.x == 0) { sb3[0] = b3[0]; sb3[1] = b3[1]; sWl = Wl[0]; sbl = bl[0]; }
    __syncthreads();

    int e = blockIdx.x * 256 + threadIdx.x;   // NE == 12500*256 exactly
    int s = eidx[e];
    int t = eidx[NE + e];

    const float4* x4 = (const float4*)xall8;
    float4 qa = x4[s * 2], qb = x4[s * 2 + 1];
    float4 qc = x4[t * 2], qd = x4[t * 2 + 1];
    float ef[13] = { qa.x, qa.y, qa.z, qa.w, qb.x, qb.y,
                     qc.x, qc.y, qc.z, qc.w, qd.x, qd.y, eg[e] };

    float h[HM], h2[HM];
    #pragma unroll
    for (int jp = 0; jp < 15; jp++) {
        float a0 = sb0p[jp].x, a1 = sb0p[jp].y;
        #pragma unroll
        for (int i = 0; i < 13; i++) {
            float2 w = sW0p[jp * 13 + i];
            a0 = fmaf(ef[i], w.x, a0);
            a1 = fmaf(ef[i], w.y, a1);
        }
        h[2 * jp] = fmaxf(a0, 0.f);
        h[2 * jp + 1] = fmaxf(a1, 0.f);
    }
    #pragma unroll
    for (int jp = 0; jp < 15; jp++) {
        float a0 = sb1p[jp].x, a1 = sb1p[jp].y;
        #pragma unroll
        for (int i = 0; i < HM; i++) {
            float2 w = sW1p[jp * 30 + i];
            a0 = fmaf(h[i], w.x, a0);
            a1 = fmaf(h[i], w.y, a1);
        }
        h2[2 * jp] = fmaxf(a0, 0.f);
        h2[2 * jp + 1] = fmaxf(a1, 0.f);
    }
    #pragma unroll
    for (int jp = 0; jp < 15; jp++) {
        float a0 = sb2p[jp].x, a1 = sb2p[jp].y;
        #pragma unroll
        for (int i = 0; i < HM; i++) {
            float2 w = sW2p[jp * 30 + i];
            a0 = fmaf(h2[i], w.x, a0);
            a1 = fmaf(h2[i], w.y, a1);
        }
        h[2 * jp] = fmaxf(a0, 0.f);
        h[2 * jp + 1] = fmaxf(a1, 0.f);
    }
    float l0 = sb3[0], l1 = sb3[1];
    #pragma unroll
    for (int i = 0; i < HM; i++) {
        float2 w = sW3[i];
        l0 = fmaf(h[i], w.x, l0);
        l1 = fmaf(h[i], w.y, l1);
    }

    const float2 g2 = ((const float2*)gum)[e];
    float v0 = l0 + g2.x;
    float v1 = l1 + g2.y;

    // forward: edge_value = (v1 > v0) ? 1 : 0; active iff edge_value == 0
    float ew = 0.f;
    if (!(v1 > v0)) {
        const float2 e2 = ((const float2*)ee)[e];
        float z = fmaf(e2.x, sWl, sbl);
        ew = e2.y / (1.f + __expf(-z));
    }
    if (ew != 0.f) {
        int slot = atomicAdd(&cnt[t], 1);
        if (slot < MAXK) {
            size_t p = (size_t)t * MAXK + slot;
            slots_w[p] = ew;
            slots_s[p] = s;
        } else {
            int i = atomicAdd(novf, 1);
            if (i < OVF_CAP) {
                ovf_w[i] = ew;
                ovf_s[i] = s;
                onxt[i] = atomicExch(&ohead[t], i);
            }
        }
    }
}

// ---------------- Stage 2: per-node deg from slots -> dis; scale xwp -------
__global__ __launch_bounds__(256) void node_deg_kernel(
    const float* __restrict__ slots_w, const int* __restrict__ cnt,
    const int* __restrict__ ohead, const int* __restrict__ onxt,
    const float* __restrict__ ovf_w,
    float* __restrict__ xwp, float* __restrict__ dis)
{
    int n = blockIdx.x * 256 + threadIdx.x;
    if (n >= NN) return;

    int c = cnt[n];
    int cc = c < MAXK ? c : MAXK;
    float deg = 0.f;
    for (int j = 0; j < cc; j++) deg += slots_w[(size_t)n * MAXK + j];
    for (int i = ohead[n]; i >= 0; i = onxt[i]) deg += ovf_w[i];

    float d = rsqrtf(deg + 1.0f);   // +1 = self loop
    dis[n] = d;

    float4* wp = (float4*)(xwp + (size_t)n * 12);
    #pragma unroll
    for (int q = 0; q < 3; q++) {
        float4 v = wp[q];
        v.x *= d; v.y *= d; v.z *= d; v.w *= d;
        wp[q] = v;
    }
}

// ---------------- Stage 3: per-node gather + epilogue (no atomics) ----------
__global__ __launch_bounds__(256) void gather_out2_kernel(
    const float* __restrict__ slots_w, const int* __restrict__ slots_s,
    const int* __restrict__ cnt,
    const int* __restrict__ ohead, const int* __restrict__ onxt,
    const float* __restrict__ ovf_w, const int* __restrict__ ovf_s,
    const float* __restrict__ z, const float* __restrict__ dis,
    const float* __restrict__ bc, const float* __restrict__ Wo,
    const float* __restrict__ bo, float* __restrict__ out)
{
    int n = blockIdx.x * 256 + threadIdx.x;
    if (n >= NN) return;

    const float4* Z = (const float4*)z;
    float4 A0 = make_float4(0.f, 0.f, 0.f, 0.f), A1 = A0, A2 = A0;

    int c = cnt[n];
    int cc = c < MAXK ? c : MAXK;
    for (int j = 0; j < cc; j++) {
        size_t p = (size_t)n * MAXK + j;
        float w = slots_w[p];
        int s = slots_s[p];
        float4 z0 = Z[s * 3], z1 = Z[s * 3 + 1], z2 = Z[s * 3 + 2];
        A0.x = fmaf(w, z0.x, A0.x); A0.y = fmaf(w, z0.y, A0.y);
        A0.z = fmaf(w, z0.z, A0.z); A0.w = fmaf(w, z0.w, A0.w);
        A1.x = fmaf(w, z1.x, A1.x); A1.y = fmaf(w, z1.y, A1.y);
        A1.z = fmaf(w, z1.z, A1.z); A1.w = fmaf(w, z1.w, A1.w);
        A2.x = fmaf(w, z2.x, A2.x); A2.y = fmaf(w, z2.y, A2.y);
    }
    for (int i = ohead[n]; i >= 0; i = onxt[i]) {
        float w = ovf_w[i];
        int s = ovf_s[i];
        float4 z0 = Z[s * 3], z1 = Z[s * 3 + 1], z2 = Z[s * 3 + 2];
        A0.x = fmaf(w, z0.x, A0.x); A0.y = fmaf(w, z0.y, A0.y);
        A0.z = fmaf(w, z0.z, A0.z); A0.w = fmaf(w, z0.w, A0.w);
        A1.x = fmaf(w, z1.x, A1.x); A1.y = fmaf(w, z1.y, A1.y);
        A1.z = fmaf(w, z1.z, A1.z); A1.w = fmaf(w, z1.w, A1.w);
        A2.x = fmaf(w, z2.x, A2.x); A2.y = fmaf(w, z2.y, A2.y);
    }

    // self loop: + z[n] (w=1), then everything * dis[n], + bc
    float4 s0 = Z[n * 3], s1 = Z[n * 3 + 1], s2 = Z[n * 3 + 2];
    A0.x += s0.x; A0.y += s0.y; A0.z += s0.z; A0.w += s0.w;
    A1.x += s1.x; A1.y += s1.y; A1.z += s1.z; A1.w += s1.w;
    A2.x += s2.x; A2.y += s2.y;

    float d = dis[n];
    float v[10] = { A0.x, A0.y, A0.z, A0.w, A1.x, A1.y, A1.z, A1.w, A2.x, A2.y };
    float o = bo[0];
    #pragma unroll
    for (int k = 0; k < HG; k++)
        o = fmaf(fmaf(v[k], d, bc[k]), Wo[k], o);
    out[n] = 1.f / (1.f + __expf(-o));
}

// ================= Fallback path (Round-1 scatter; unused when ws fits) =====
__global__ __launch_bounds__(256) void edge_mlp_kernel(
    const float* __restrict__ x, const float* __restrict__ token,
    const float* __restrict__ eg, const float* __restrict__ ee,
    const float* __restrict__ gum, const int* __restrict__ eidx,
    const float* __restrict__ W0, const float* __restrict__ b0,
    const float* __restrict__ W1, const float* __restrict__ b1,
    const float* __restrict__ W2, const float* __restrict__ b2,
    const float* __restrict__ W3, const float* __restrict__ b3,
    const float* __restrict__ Wl, const float* __restrict__ bl,
    float* __restrict__ ew_out, float* __restrict__ deg)
{
    int e = blockIdx.x * 256 + threadIdx.x;
    if (e >= NE) return;
    int s = eidx[e];
    int t = eidx[NE + e];

    float ef[13];
    ef[0] = x[s];
    #pragma unroll
    for (int i = 0; i < 5; i++) ef[1 + i] = token[s * 5 + i];
    ef[6] = x[t];
    #pragma unroll
    for (int i = 0; i < 5; i++) ef[7 + i] = token[t * 5 + i];
    ef[12] = eg[e];

    float h[HM], h2[HM];
    #pragma unroll
    for (int j = 0; j < HM; j++) {
        float a = b0[j];
        #pragma unroll
        for (int i = 0; i < 13; i++) a = fmaf(ef[i], W0[i * HM + j], a);
        h[j] = fmaxf(a, 0.f);
    }
    #pragma unroll
    for (int j = 0; j < HM; j++) {
        float a = b1[j];
        #pragma unroll
        for (int i = 0; i < HM; i++) a = fmaf(h[i], W1[i * HM + j], a);
        h2[j] = fmaxf(a, 0.f);
    }
    #pragma unroll
    for (int j = 0; j < HM; j++) {
        float a = b2[j];
        #pragma unroll
        for (int i = 0; i < HM; i++) a = fmaf(h2[i], W2[i * HM + j], a);
        h[j] = fmaxf(a, 0.f);
    }
    float l0 = b3[0], l1 = b3[1];
    #pragma unroll
    for (int i = 0; i < HM; i++) {
        l0 = fmaf(h[i], W3[i * 2 + 0], l0);
        l1 = fmaf(h[i], W3[i * 2 + 1], l1);
    }
    const float2 g2 = ((const float2*)gum)[e];
    float v0 = l0 + g2.x, v1 = l1 + g2.y;
    float ew = 0.f;
    if (!(v1 > v0)) {
        const float2 ee2 = ((const float2*)ee)[e];
        float z = fmaf(ee2.x, Wl[0], bl[0]);
        ew = ee2.y / (1.f + __expf(-z));
    }
    ew_out[e] = ew;
    if (ew != 0.f) atomicAdd(&deg[t], ew);
}

__global__ __launch_bounds__(256) void node_pre_kernel(
    const float* __restrict__ x, const float* __restrict__ token,
    const float* __restrict__ Wc, const float* __restrict__ deg,
    float* __restrict__ xw, float* __restrict__ dis)
{
    int n = blockIdx.x * 256 + threadIdx.x;
    if (n >= NN) return;
    float xa[6];
    xa[0] = x[n];
    #pragma unroll
    for (int i = 0; i < 5; i++) xa[1 + i] = token[n * 5 + i];
    #pragma unroll
    for (int k = 0; k < HG; k++) {
        float a = 0.f;
        #pragma unroll
        for (int i = 0; i < 6; i++) a = fmaf(xa[i], Wc[i * HG + k], a);
        xw[n * HG + k] = a;
    }
    dis[n] = rsqrtf(deg[n] + 1.0f);
}

__global__ __launch_bounds__(256) void edge_scatter_kernel(
    const int* __restrict__ eidx, const float* __restrict__ ew,
    const float* __restrict__ dis, const float* __restrict__ xw,
    float* __restrict__ agg)
{
    int e = blockIdx.x * 256 + threadIdx.x;
    if (e >= NE) return;
    float w = ew[e];
    if (w == 0.f) return;
    int s = eidx[e];
    int t = eidx[NE + e];
    float norm = dis[s] * w * dis[t];
    #pragma unroll
    for (int k = 0; k < HG; k++)
        atomicAdd(&agg[t * HG + k], norm * xw[s * HG + k]);
}

__global__ __launch_bounds__(256) void node_out_kernel(
    const float* __restrict__ agg, const float* __restrict__ xw,
    const float* __restrict__ dis, const float* __restrict__ bc,
    const float* __restrict__ Wo, const float* __restrict__ bo,
    float* __restrict__ out)
{
    int n = blockIdx.x * 256 + threadIdx.x;
    if (n >= NN) return;
    float d = dis[n];
    float self = d * d;
    float acc = bo[0];
    #pragma unroll
    for (int k = 0; k < HG; k++) {
        float v = agg[n * HG + k] + xw[n * HG + k] * self + bc[k];
        acc = fmaf(v, Wo[k], acc);
    }
    out[n] = 1.f / (1.f + __expf(-acc));
}

extern "C" void kernel_launch(void* const* d_in, const int* in_sizes, int n_in,
                              void* d_out, int out_size, void* d_ws, size_t ws_size,
                              hipStream_t stream) {
    const float* x   = (const float*)d_in[0];
    const float* tok = (const float*)d_in[1];
    const float* eg  = (const float*)d_in[2];
    const float* ee  = (const float*)d_in[3];
    const float* gum = (const float*)d_in[4];
    const int*   ei  = (const int*)d_in[5];
    const float* W0  = (const float*)d_in[6];
    const float* b0  = (const float*)d_in[7];
    const float* W1  = (const float*)d_in[8];
    const float* b1  = (const float*)d_in[9];
    const float* W2  = (const float*)d_in[10];
    const float* b2  = (const float*)d_in[11];
    const float* W3  = (const float*)d_in[12];
    const float* b3  = (const float*)d_in[13];
    const float* Wl  = (const float*)d_in[14];
    const float* bl  = (const float*)d_in[15];
    const float* Wc  = (const float*)d_in[16];
    const float* bc  = (const float*)d_in[17];
    const float* Wo  = (const float*)d_in[18];
    const float* bo  = (const float*)d_in[19];
    float* out = (float*)d_out;

    dim3 blk(256);
    dim3 egrid(NE / 256);               // exact: 12500
    dim3 ngrid((NN + 255) / 256);

    // ws layout (float offsets) — slots split SoA; total ~30.1 MB (fits, R3-proven)
    size_t off_xall8 = 0;                                 // NN*8
    size_t off_z     = off_xall8 + (size_t)NN * 8;        // NN*12
    size_t off_sw    = off_z + (size_t)NN * 12;           // NN*MAXK float
    size_t off_ss    = off_sw + (size_t)NN * MAXK;        // NN*MAXK int
    size_t off_cnt   = off_ss + (size_t)NN * MAXK;        // NN int
    size_t off_novf  = off_cnt + NN;                      // 1 int
    size_t off_dis   = off_novf + 1;                      // NN
    size_t off_ohead = off_dis + NN;                      // NN int
    size_t off_ovfw  = off_ohead + NN;                    // OVF_CAP
    size_t off_ovfs  = off_ovfw + OVF_CAP;                // OVF_CAP int
    size_t off_onxt  = off_ovfs + OVF_CAP;                // OVF_CAP int
    size_t need_new  = (off_onxt + OVF_CAP) * sizeof(float);

    if (ws_size >= need_new) {
        float*  ws      = (float*)d_ws;
        float*  xall8   = ws + off_xall8;
        float*  z       = ws + off_z;
        float*  slots_w = ws + off_sw;
        int*    slots_s = (int*)(ws + off_ss);
        int*    cnt     = (int*)(ws + off_cnt);
        int*    novf    = (int*)(ws + off_novf);
        float*  dis     = ws + off_dis;
        int*    ohead   = (int*)(ws + off_ohead);
        float*  ovf_w   = ws + off_ovfw;
        int*    ovf_s   = (int*)(ws + off_ovfs);
        int*    onxt    = (int*)(ws + off_onxt);

        hipMemsetAsync(cnt, 0, (size_t)(NN + 1) * sizeof(int), stream);   // cnt + novf
        hipMemsetAsync(ohead, 0xFF, (size_t)NN * sizeof(int), stream);    // ohead = -1

        pack_kernel<<<ngrid, blk, 0, stream>>>(x, tok, Wc, xall8, z);
        edge_mlp4_kernel<<<egrid, blk, 0, stream>>>(xall8, eg, ee, gum, ei,
                                                    W0, b0, W1, b1, W2, b2, W3, b3,
                                                    Wl, bl, slots_w, slots_s, cnt,
                                                    ohead, onxt, ovf_w, ovf_s, novf);
        node_deg_kernel<<<ngrid, blk, 0, stream>>>(slots_w, cnt, ohead, onxt, ovf_w,
                                                   z, dis);
        gather_out2_kernel<<<ngrid, blk, 0, stream>>>(slots_w, slots_s, cnt,
                                                      ohead, onxt, ovf_w, ovf_s,
                                                      z, dis, bc, Wo, bo, out);
    } else {
        // Fallback: Round-1 scatter layout: [ew: NE][deg: NN][agg: NN*HG][xw: NN*HG][dis: NN]
        float* ws  = (float*)d_ws;
        float* ew  = ws;
        float* deg = ew + NE;
        float* agg = deg + NN;
        float* xw  = agg + (size_t)NN * HG;
        float* dis = xw + (size_t)NN * HG;

        hipMemsetAsync(deg, 0, (size_t)(NN + (size_t)NN * HG) * sizeof(float), stream);
        edge_mlp_kernel<<<egrid, blk, 0, stream>>>(x, tok, eg, ee, gum, ei,
                                                   W0, b0, W1, b1, W2, b2, W3, b3,
                                                   Wl, bl, ew, deg);
        node_pre_kernel<<<ngrid, blk, 0, stream>>>(x, tok, Wc, deg, xw, dis);
        edge_scatter_kernel<<<egrid, blk, 0, stream>>>(ei, ew, dis, xw, agg);
        node_out_kernel<<<ngrid, blk, 0, stream>>>(agg, xw, dis, bc, Wo, bo, out);
    }
}